// Round 3
// baseline (1302.561 us; speedup 1.0000x reference)
//
#include <hip/hip_runtime.h>
#include <stdint.h>

typedef unsigned short u16;
typedef __attribute__((ext_vector_type(8))) short short8;
typedef __attribute__((ext_vector_type(4))) float f32x4;

#define NB 32
#define PP 1024
#define SEQ 128
#define EE 768
#define HH 8
#define DD 96
#define NCC 5
#define NLL 3

__device__ __forceinline__ float bf2f(u16 x){ unsigned u=((unsigned)x)<<16; float f; __builtin_memcpy(&f,&u,4); return f; }
__device__ __forceinline__ u16 f2bf(float f){ unsigned u; __builtin_memcpy(&u,&f,4); u=(u+0x7FFFu+((u>>16)&1u))>>16; return (u16)u; }

__device__ __forceinline__ short8 cvt8(const float* p) {
  f32x4 a = *(const f32x4*)p;
  f32x4 b = *(const f32x4*)(p+4);
  short8 r;
  r[0]=(short)f2bf(a[0]); r[1]=(short)f2bf(a[1]); r[2]=(short)f2bf(a[2]); r[3]=(short)f2bf(a[3]);
  r[4]=(short)f2bf(b[0]); r[5]=(short)f2bf(b[1]); r[6]=(short)f2bf(b[2]); r[7]=(short)f2bf(b[3]);
  return r;
}

// ---------------- block LN stats helper (256 threads, 3 vals/thread) --------
__device__ __forceinline__ void ln_stats(float v0, float v1, float v2, float* red, int t,
                                         float& mean, float& rstd) {
  float ps = v0+v1+v2;
  float ps2 = v0*v0+v1*v1+v2*v2;
  #pragma unroll
  for (int o=32;o;o>>=1){ ps += __shfl_down(ps,o,64); ps2 += __shfl_down(ps2,o,64); }
  if ((t&63)==0){ red[t>>6]=ps; red[4+(t>>6)]=ps2; }
  __syncthreads();
  mean = (red[0]+red[1]+red[2]+red[3])*(1.0f/EE);
  float var = (red[4]+red[5]+red[6]+red[7])*(1.0f/EE) - mean*mean;
  rstd = rsqrtf(var + 1e-5f);
  __syncthreads();
}

// ---------------- generic GEMM: C[m,n] = sum_k A[m,k]*B[n,k] + bias[n] ------
// AF/BF: A/B source is f32 (convert to bf16 during staging) vs bf16.
// EPI 0: bf16 store to C (ld=N). EPI 1: bf16 store + f32 residual Res (ld=N).
// EPI 2: KV split: col<768 -> C (kh bf16, ld=768); col>=768 -> C2 as V^T bf16:
//        C2[( (row>>7)*768 + (col-768) )*128 + (row&127)]
// EPI 3: f32 store to Cf (ld=N).
#define BMT 128
#define BNT 128
#define LDK 40

template<int EPI, int AF, int BF>
__global__ __launch_bounds__(256) void gemm_bt(const void* __restrict__ Av, const void* __restrict__ Bv,
        const float* __restrict__ bias, const float* __restrict__ Res,
        u16* __restrict__ C, float* __restrict__ Cf, u16* __restrict__ C2, int M, int N, int K)
{
  __shared__ u16 As[BMT*LDK];
  __shared__ u16 Bs[BNT*LDK];
  const int m0 = blockIdx.x*BMT, n0 = blockIdx.y*BNT;
  const int t = threadIdx.x;
  const int l = t&63, w = t>>6, wr = w>>1, wc = w&1, lm = l&15, lg = l>>4;
  const int srow = t>>1, scol = (t&1)*16;
  f32x4 acc[4][4] = {};
  for (int k0=0; k0<K; k0+=32) {
    short8 a0,a1,b0,b1;
    if constexpr (AF) {
      const float* p = (const float*)Av + (size_t)(m0+srow)*K + scol + k0;
      a0 = cvt8(p); a1 = cvt8(p+8);
    } else {
      const u16* p = (const u16*)Av + (size_t)(m0+srow)*K + scol + k0;
      a0 = *(const short8*)p; a1 = *(const short8*)(p+8);
    }
    if constexpr (BF) {
      const float* p = (const float*)Bv + (size_t)(n0+srow)*K + scol + k0;
      b0 = cvt8(p); b1 = cvt8(p+8);
    } else {
      const u16* p = (const u16*)Bv + (size_t)(n0+srow)*K + scol + k0;
      b0 = *(const short8*)p; b1 = *(const short8*)(p+8);
    }
    __syncthreads();
    *(short8*)&As[srow*LDK+scol]   = a0;
    *(short8*)&As[srow*LDK+scol+8] = a1;
    *(short8*)&Bs[srow*LDK+scol]   = b0;
    *(short8*)&Bs[srow*LDK+scol+8] = b1;
    __syncthreads();
    short8 af[4], bfv[4];
    #pragma unroll
    for (int mi=0;mi<4;mi++) af[mi]  = *(const short8*)&As[(wr*64+mi*16+lm)*LDK + lg*8];
    #pragma unroll
    for (int ni=0;ni<4;ni++) bfv[ni] = *(const short8*)&Bs[(wc*64+ni*16+lm)*LDK + lg*8];
    #pragma unroll
    for (int mi=0;mi<4;mi++)
      #pragma unroll
      for (int ni=0;ni<4;ni++)
        acc[mi][ni] = __builtin_amdgcn_mfma_f32_16x16x32_bf16(af[mi], bfv[ni], acc[mi][ni], 0,0,0);
  }
  #pragma unroll
  for (int mi=0;mi<4;mi++) {
    #pragma unroll
    for (int ni=0;ni<4;ni++) {
      const int col = n0 + wc*64 + ni*16 + lm;
      const float bv = bias[col];
      #pragma unroll
      for (int r=0;r<4;r++) {
        const int row = m0 + wr*64 + mi*16 + lg*4 + r;
        float v = acc[mi][ni][r] + bv;
        if constexpr (EPI==1) v += Res[(size_t)row*N + col];
        if constexpr (EPI==3) {
          Cf[(size_t)row*N + col] = v;
        } else if constexpr (EPI==2) {
          if (col < EE) C[(size_t)row*EE + col] = f2bf(v);
          else C2[((size_t)(row>>7)*EE + (col-EE))*SEQ + (row&127)] = f2bf(v);
        } else {
          C[(size_t)row*N + col] = f2bf(v);
        }
      }
    }
  }
}

// ---------------- fused attention: per (b, h, 64-row q-tile) ----------------
// Q (in/out, bf16 [B*P, E] slice at h*96), K bf16 [B*S, E], Vt bf16 [(b*8+h)*96, 128]
__global__ __launch_bounds__(256) void attn_k(u16* __restrict__ Q, const u16* __restrict__ Kb,
                                              const u16* __restrict__ Vt)
{
  const int qt = blockIdx.x, h = blockIdx.y, b = blockIdx.z;
  const int t = threadIdx.x, l = t&63, w = t>>6, wr = w>>1, wc = w&1, lm = l&15, lg = l>>4;
  __shared__ u16 Ps[64][136];
  __shared__ float redm[2][64];
  __shared__ float reds[2][64];
  u16* qb = Q + ((size_t)(b*PP + qt*64))*EE + h*DD;
  const u16* kb = Kb + ((size_t)b*SEQ)*EE + h*DD;
  const u16* vb = Vt + ((size_t)(b*HH+h))*DD*SEQ;

  // scores: wave tile 32 rows x 64 cols; K = 96 (3 MFMA chunks)
  f32x4 acc[2][4] = {};
  #pragma unroll
  for (int kc=0;kc<3;kc++) {
    short8 af[2], bv[4];
    #pragma unroll
    for (int mi=0;mi<2;mi++) af[mi] = *(const short8*)(qb + (size_t)(wr*32+mi*16+lm)*EE + kc*32 + lg*8);
    #pragma unroll
    for (int ni=0;ni<4;ni++) bv[ni] = *(const short8*)(kb + (size_t)(wc*64+ni*16+lm)*EE + kc*32 + lg*8);
    #pragma unroll
    for (int mi=0;mi<2;mi++)
      #pragma unroll
      for (int ni=0;ni<4;ni++)
        acc[mi][ni] = __builtin_amdgcn_mfma_f32_16x16x32_bf16(af[mi], bv[ni], acc[mi][ni], 0,0,0);
  }
  const float scale = 0.1020620726159658f; // 1/sqrt(96)
  float gmax[2][4], gsum[2][4];
  #pragma unroll
  for (int mi=0;mi<2;mi++)
    #pragma unroll
    for (int r=0;r<4;r++) {
      float v = fmaxf(fmaxf(acc[mi][0][r],acc[mi][1][r]),fmaxf(acc[mi][2][r],acc[mi][3][r]));
      #pragma unroll
      for (int mk=1;mk<16;mk<<=1) v = fmaxf(v, __shfl_xor(v,mk,64));
      gmax[mi][r]=v;
    }
  if (lm==0) {
    #pragma unroll
    for (int mi=0;mi<2;mi++)
      #pragma unroll
      for (int r=0;r<4;r++) redm[wc][wr*32+mi*16+lg*4+r] = gmax[mi][r];
  }
  __syncthreads();
  #pragma unroll
  for (int mi=0;mi<2;mi++)
    #pragma unroll
    for (int r=0;r<4;r++) {
      const int row = wr*32+mi*16+lg*4+r;
      gmax[mi][r] = fmaxf(redm[0][row], redm[1][row]);
    }
  #pragma unroll
  for (int mi=0;mi<2;mi++)
    #pragma unroll
    for (int r=0;r<4;r++) {
      float s=0.f;
      #pragma unroll
      for (int ni=0;ni<4;ni++) {
        float p = __expf((acc[mi][ni][r]-gmax[mi][r])*scale);
        acc[mi][ni][r]=p; s+=p;
      }
      #pragma unroll
      for (int mk=1;mk<16;mk<<=1) s += __shfl_xor(s,mk,64);
      gsum[mi][r]=s;
    }
  __syncthreads();
  if (lm==0) {
    #pragma unroll
    for (int mi=0;mi<2;mi++)
      #pragma unroll
      for (int r=0;r<4;r++) reds[wc][wr*32+mi*16+lg*4+r] = gsum[mi][r];
  }
  __syncthreads();
  #pragma unroll
  for (int mi=0;mi<2;mi++)
    #pragma unroll
    for (int r=0;r<4;r++) {
      const int row = wr*32+mi*16+lg*4+r;
      const float inv = 1.0f/(reds[0][row]+reds[1][row]);
      #pragma unroll
      for (int ni=0;ni<4;ni++)
        Ps[row][wc*64+ni*16+lm] = f2bf(acc[mi][ni][r]*inv);
    }
  __syncthreads();

  // PV: out tile 64x96; wave tile 32 rows x 48 cols; K = 128 (4 chunks)
  f32x4 oacc[2][3] = {};
  #pragma unroll
  for (int kc=0;kc<4;kc++) {
    short8 pa[2], vv[3];
    #pragma unroll
    for (int mi=0;mi<2;mi++) pa[mi] = *(const short8*)&Ps[wr*32+mi*16+lm][kc*32+lg*8];
    #pragma unroll
    for (int ni=0;ni<3;ni++) vv[ni] = *(const short8*)(vb + (size_t)(wc*48+ni*16+lm)*SEQ + kc*32 + lg*8);
    #pragma unroll
    for (int mi=0;mi<2;mi++)
      #pragma unroll
      for (int ni=0;ni<3;ni++)
        oacc[mi][ni] = __builtin_amdgcn_mfma_f32_16x16x32_bf16(pa[mi], vv[ni], oacc[mi][ni], 0,0,0);
  }
  #pragma unroll
  for (int mi=0;mi<2;mi++)
    #pragma unroll
    for (int ni=0;ni<3;ni++)
      #pragma unroll
      for (int r=0;r<4;r++)
        qb[(size_t)(wr*32+mi*16+lg*4+r)*EE + wc*48+ni*16+lm] = f2bf(oacc[mi][ni][r]);
}

// ---------------- graph: per (l,c) node update + k-projection (batch-indep) -
__global__ __launch_bounds__(256) void k_upd(const float* __restrict__ node_all, const float* __restrict__ edge_all,
    const float* __restrict__ W1a, const float* __restrict__ b1a,
    const float* __restrict__ lnga, const float* __restrict__ lnba,
    const float* __restrict__ W2a, const float* __restrict__ b2a,
    const float* __restrict__ Wqkva, const float* __restrict__ bqkva,
    float* __restrict__ upd, float* __restrict__ khg)
{
  const int lc = blockIdx.x, l = lc/NCC, c = lc%NCC, t = threadIdx.x;
  __shared__ float comb[2*EE];
  __shared__ float hbuf[EE];
  __shared__ float red[8];
  const float* node = node_all + (size_t)l*NCC*EE;
  const float* edge = edge_all + (size_t)l*3*EE;
  for (int e=t;e<EE;e+=256) {
    float n0=node[e], n1=node[EE+e], n2=node[2*EE+e], n3=node[3*EE+e];
    float nc_=node[(size_t)c*EE+e];
    float e0=edge[e], e1=edge[EE+e], e2=edge[2*EE+e];
    float s0;
    if (c==0) s0=n1+n2; else if (c==1) s0=n0+n2; else if (c==2) s0=n0+n1+n3; else if (c==3) s0=n2; else s0=0.f;
    float ef = (s0*e0 + ((c==3)? n2*e1 : 0.f) + nc_*e2)*(1.0f/3.0f);
    comb[e]=nc_; comb[EE+e]=ef;
  }
  __syncthreads();
  const float* W1 = W1a + (size_t)l*EE*2*EE;
  const float* b1 = b1a + l*EE;
  float hv[3];
  #pragma unroll
  for (int i=0;i<3;i++) {
    const int f=t+i*256;
    const float* wrow = W1 + (size_t)f*2*EE;
    float a = b1[f];
    for (int k=0;k<2*EE;k+=4) {
      f32x4 w4 = *(const f32x4*)(wrow+k);
      a += comb[k]*w4[0]+comb[k+1]*w4[1]+comb[k+2]*w4[2]+comb[k+3]*w4[3];
    }
    hv[i]=a;
  }
  float mean, rstd;
  ln_stats(hv[0],hv[1],hv[2], red, t, mean, rstd);
  const float* lng = lnga + l*EE; const float* lnb = lnba + l*EE;
  #pragma unroll
  for (int i=0;i<3;i++){ const int f=t+i*256;
    float x=(hv[i]-mean)*rstd*lng[f]+lnb[f]; hbuf[f]=fmaxf(x,0.f); }
  __syncthreads();
  const float* W2 = W2a + (size_t)l*EE*EE; const float* b2 = b2a + l*EE;
  float uv[3];
  #pragma unroll
  for (int i=0;i<3;i++) {
    const int e=t+i*256;
    const float* wrow = W2 + (size_t)e*EE;
    float a = b2[e];
    for (int k=0;k<EE;k+=4) {
      f32x4 w4 = *(const f32x4*)(wrow+k);
      a += hbuf[k]*w4[0]+hbuf[k+1]*w4[1]+hbuf[k+2]*w4[2]+hbuf[k+3]*w4[3];
    }
    uv[i]=a; upd[(size_t)lc*EE+e]=a;
  }
  __syncthreads();
  #pragma unroll
  for (int i=0;i<3;i++) comb[t+i*256]=uv[i];
  __syncthreads();
  const float* Wk = Wqkva + (size_t)l*3*EE*EE + (size_t)EE*EE;
  const float* bk = bqkva + (size_t)l*3*EE + EE;
  #pragma unroll
  for (int i=0;i<3;i++) {
    const int j=t+i*256;
    const float* wrow = Wk + (size_t)j*EE;
    float a = bk[j];
    for (int k=0;k<EE;k+=4) {
      f32x4 w4 = *(const f32x4*)(wrow+k);
      a += comb[k]*w4[0]+comb[k+1]*w4[1]+comb[k+2]*w4[2]+comb[k+3]*w4[3];
    }
    khg[(size_t)lc*EE+j]=a;
  }
}

__global__ __launch_bounds__(256) void k_sent_init(const float* __restrict__ se, float* __restrict__ sent) {
  const int i = blockIdx.x*256 + threadIdx.x;
  if (i < NB*EE) sent[i] = se[i];
}

// ---------------- graph: per-batch attention + sent update (sequential in l) -
__global__ __launch_bounds__(256) void k_attn(int l, const float* __restrict__ Wqkva, const float* __restrict__ bqkva,
    const float* __restrict__ presence, const float* __restrict__ upd, const float* __restrict__ khg,
    float* __restrict__ sent, float* __restrict__ sc_ws, float* __restrict__ out_scores)
{
  const int b = blockIdx.x, t = threadIdx.x;
  __shared__ float sbuf[EE];
  __shared__ float qh[EE];
  __shared__ float scl[HH][NCC];
  __shared__ float wsc[NCC];
  __shared__ float scr[NCC];
  #pragma unroll
  for (int i=0;i<3;i++){ const int e=t+i*256; sbuf[e]=sent[(size_t)b*EE+e]; }
  __syncthreads();
  const float* Wq = Wqkva + (size_t)l*3*EE*EE;
  const float* bq = bqkva + (size_t)l*3*EE;
  #pragma unroll
  for (int i=0;i<3;i++) {
    const int j=t+i*256;
    const float* wrow = Wq + (size_t)j*EE;
    float a = bq[j];
    for (int k=0;k<EE;k+=4) {
      f32x4 w4 = *(const f32x4*)(wrow+k);
      a += sbuf[k]*w4[0]+sbuf[k+1]*w4[1]+sbuf[k+2]*w4[2]+sbuf[k+3]*w4[3];
    }
    qh[j]=a;
  }
  __syncthreads();
  if (t < HH*NCC) {
    const int hh=t/NCC, cc=t%NCC;
    const float* kr = khg + (size_t)(l*NCC+cc)*EE + hh*DD;
    float a=0.f;
    #pragma unroll 8
    for (int d=0;d<DD;d++) a += qh[hh*DD+d]*kr[d];
    scl[hh][cc]=a*0.1020620726159658f;
  }
  __syncthreads();
  if (t < HH) {
    float m=scl[t][0];
    #pragma unroll
    for (int c2=1;c2<NCC;c2++) m=fmaxf(m,scl[t][c2]);
    float ex[NCC]; float s=0.f;
    #pragma unroll
    for (int c2=0;c2<NCC;c2++){ ex[c2]=__expf(scl[t][c2]-m); s+=ex[c2]; }
    #pragma unroll
    for (int c2=0;c2<NCC;c2++) scl[t][c2]=ex[c2]/s;
  }
  __syncthreads();
  if (t < NCC) {
    float wv=0.f;
    #pragma unroll
    for (int hh=0;hh<HH;hh++) wv += scl[hh][t];
    wv *= (1.0f/HH);
    wsc[t] = wv*(presence[b*NCC+t]+0.1f);
  }
  __syncthreads();
  if (t==0) {
    float m=wsc[0];
    #pragma unroll
    for (int c2=1;c2<NCC;c2++) m=fmaxf(m,wsc[c2]);
    float ex[NCC]; float s=0.f;
    #pragma unroll
    for (int c2=0;c2<NCC;c2++){ ex[c2]=__expf(wsc[c2]-m); s+=ex[c2]; }
    #pragma unroll
    for (int c2=0;c2<NCC;c2++){
      float v=ex[c2]/s; scr[c2]=v; sc_ws[b*NCC+c2]=v;
      if (out_scores) out_scores[b*NCC+c2]=v;
    }
  }
  __syncthreads();
  #pragma unroll
  for (int i=0;i<3;i++) {
    const int e=t+i*256;
    float a=0.f;
    #pragma unroll
    for (int c2=0;c2<NCC;c2++) a += scr[c2]*upd[(size_t)(l*NCC+c2)*EE+e];
    sent[(size_t)b*EE+e] = sbuf[e] + a*(1.0f/NCC);
  }
}

// ---------------- row LayerNorm in-place (bf16 data, f32 params) -------------
__global__ __launch_bounds__(256) void k_ln(u16* __restrict__ G, const float* __restrict__ gw, const float* __restrict__ gb)
{
  const int row = blockIdx.x, t = threadIdx.x;
  u16* p = G + (size_t)row*EE;
  __shared__ float red[8];
  float v[3];
  #pragma unroll
  for (int i=0;i<3;i++) v[i]=bf2f(p[t+i*256]);
  float mean, rstd;
  ln_stats(v[0],v[1],v[2], red, t, mean, rstd);
  #pragma unroll
  for (int i=0;i<3;i++) {
    const int e=t+i*256;
    p[e]=f2bf((v[i]-mean)*rstd*gw[e]+gb[e]);
  }
}

// ---------------- per-(b,c) class guidance chain -----------------------------
__global__ __launch_bounds__(256) void k_class(const float* __restrict__ upd, const float* __restrict__ sc_ws,
    const float* __restrict__ sent,
    const float* __restrict__ cW1, const float* __restrict__ cb1, const float* __restrict__ clng, const float* __restrict__ clnb,
    const float* __restrict__ cW2, const float* __restrict__ cb2,
    const float* __restrict__ gfW1, const float* __restrict__ gfb1, const float* __restrict__ gflng, const float* __restrict__ gflnb,
    const float* __restrict__ gfW2, const float* __restrict__ gfb2,
    float* __restrict__ outCG)
{
  const int bid = blockIdx.x, b = bid/NCC, c = bid%NCC, t = threadIdx.x;
  __shared__ float act[EE];
  __shared__ float buf[EE];
  __shared__ float cat[2*EE];
  __shared__ float red[8];
  const float sc = sc_ws[b*NCC+c];
  #pragma unroll
  for (int i=0;i<3;i++){ const int e=t+i*256; act[e]=upd[(size_t)(2*NCC+c)*EE+e]*sc; }
  __syncthreads();
  float hv[3]; float mean, rstd;
  // cf1 = act @ cW1[c]^T + cb1[c]; relu(LN)
  #pragma unroll
  for (int i=0;i<3;i++) {
    const int f=t+i*256;
    const float* wrow = cW1 + (size_t)(c*EE+f)*EE;
    float a = cb1[c*EE+f];
    for (int k=0;k<EE;k+=4) {
      f32x4 w4=*(const f32x4*)(wrow+k);
      a += act[k]*w4[0]+act[k+1]*w4[1]+act[k+2]*w4[2]+act[k+3]*w4[3];
    }
    hv[i]=a;
  }
  ln_stats(hv[0],hv[1],hv[2], red, t, mean, rstd);
  #pragma unroll
  for (int i=0;i<3;i++){ const int f=t+i*256;
    buf[f]=fmaxf((hv[i]-mean)*rstd*clng[c*EE+f]+clnb[c*EE+f],0.f); }
  __syncthreads();
  // cf2 -> cat[0:768]; cat[768:1536] = sent
  #pragma unroll
  for (int i=0;i<3;i++) {
    const int e=t+i*256;
    const float* wrow = cW2 + (size_t)(c*EE+e)*EE;
    float a = cb2[c*EE+e];
    for (int k=0;k<EE;k+=4) {
      f32x4 w4=*(const f32x4*)(wrow+k);
      a += buf[k]*w4[0]+buf[k+1]*w4[1]+buf[k+2]*w4[2]+buf[k+3]*w4[3];
    }
    cat[e]=a; cat[EE+e]=sent[(size_t)b*EE+e];
  }
  __syncthreads();
  // g = cat @ gfW1^T + gfb1; relu(LN) -> buf
  #pragma unroll
  for (int i=0;i<3;i++) {
    const int f=t+i*256;
    const float* wrow = gfW1 + (size_t)f*2*EE;
    float a = gfb1[f];
    for (int k=0;k<2*EE;k+=4) {
      f32x4 w4=*(const f32x4*)(wrow+k);
      a += cat[k]*w4[0]+cat[k+1]*w4[1]+cat[k+2]*w4[2]+cat[k+3]*w4[3];
    }
    hv[i]=a;
  }
  ln_stats(hv[0],hv[1],hv[2], red, t, mean, rstd);
  __syncthreads();
  #pragma unroll
  for (int i=0;i<3;i++){ const int f=t+i*256;
    buf[f]=fmaxf((hv[i]-mean)*rstd*gflng[f]+gflnb[f],0.f); }
  __syncthreads();
  // cg = buf @ gfW2^T + gfb2
  #pragma unroll
  for (int i=0;i<3;i++) {
    const int e=t+i*256;
    const float* wrow = gfW2 + (size_t)e*EE;
    float a = gfb2[e];
    for (int k=0;k<EE;k+=4) {
      f32x4 w4=*(const f32x4*)(wrow+k);
      a += buf[k]*w4[0]+buf[k+1]*w4[1]+buf[k+2]*w4[2]+buf[k+3]*w4[3];
    }
    outCG[(size_t)bid*EE+e]=a;
  }
}

// ---------------- host launch ------------------------------------------------
extern "C" void kernel_launch(void* const* d_in, const int* in_sizes, int n_in,
                              void* d_out, int out_size, void* d_ws, size_t ws_size,
                              hipStream_t stream)
{
  const float* visual   = (const float*)d_in[0];
  const float* text     = (const float*)d_in[1];
  const float* sentemb  = (const float*)d_in[2];
  const float* presence = (const float*)d_in[3];
  const float* gnode = (const float*)d_in[4];
  const float* gedge = (const float*)d_in[5];
  const float* gWqkv = (const float*)d_in[6];
  const float* gbqkv = (const float*)d_in[7];
  const float* gW1 = (const float*)d_in[10];
  const float* gb1 = (const float*)d_in[11];
  const float* glng = (const float*)d_in[12];
  const float* glnb = (const float*)d_in[13];
  const float* gW2 = (const float*)d_in[14];
  const float* gb2 = (const float*)d_in[15];
  const float* vWqkv = (const float*)d_in[16];
  const float* vbqkv = (const float*)d_in[17];
  const float* vWo = (const float*)d_in[18];
  const float* vbo = (const float*)d_in[19];
  const float* cW1 = (const float*)d_in[20];
  const float* cb1 = (const float*)d_in[21];
  const float* clng = (const float*)d_in[22];
  const float* clnb = (const float*)d_in[23];
  const float* cW2 = (const float*)d_in[24];
  const float* cb2 = (const float*)d_in[25];
  const float* gfW1 = (const float*)d_in[26];
  const float* gfb1 = (const float*)d_in[27];
  const float* gflng = (const float*)d_in[28];
  const float* gflnb = (const float*)d_in[29];
  const float* gfW2 = (const float*)d_in[30];
  const float* gfb2 = (const float*)d_in[31];
  const float* outW = (const float*)d_in[32];
  const float* outb = (const float*)d_in[33];
  const float* normg = (const float*)d_in[34];
  const float* normb = (const float*)d_in[35];

  char* ws = (char*)d_ws;
  u16* wsQ  = (u16*)(ws);                     // 32768x768 bf16 (Q, then attn out in-place)
  u16* wsK  = (u16*)(ws + 50331648);          // 4096x768 bf16
  u16* wsVt = (u16*)(ws + 56623104);          // (32*8*96)x128 bf16 (V transposed)
  u16* wsG  = (u16*)(ws + 62914560);          // 32768x768 bf16 (pre-LN, then grounded in-place)
  float* wsSent   = (float*)(ws + 113246208); // 32x768
  float* wsUpd    = (float*)(ws + 113246208 + 98304);           // 15x768
  float* wsKhg    = (float*)(ws + 113246208 + 98304 + 46080);   // 15x768
  float* wsScores = (float*)(ws + 113246208 + 98304 + 92160);   // 32x5

  float* outGO = (float*)d_out;
  float* outCG = outGO + 25165824;
  float* outSC = outGO + 25288704;

  // graph precompute (batch-independent node updates, all layers)
  k_upd<<<dim3(NLL*NCC), dim3(256), 0, stream>>>(gnode, gedge, gW1, gb1, glng, glnb, gW2, gb2,
                                                 gWqkv, gbqkv, wsUpd, wsKhg);
  k_sent_init<<<dim3(96), dim3(256), 0, stream>>>(sentemb, wsSent);
  for (int l=0;l<NLL;l++)
    k_attn<<<dim3(NB), dim3(256), 0, stream>>>(l, gWqkv, gbqkv, presence, wsUpd, wsKhg,
                                               wsSent, wsScores, (l==NLL-1)?outSC:(float*)nullptr);

  // visual-text fusion
  gemm_bt<0,1,1><<<dim3(256,6), dim3(256), 0, stream>>>(visual, vWqkv, vbqkv, nullptr,
                                                        wsQ, nullptr, nullptr, NB*PP, EE, EE);
  gemm_bt<2,1,1><<<dim3(32,12), dim3(256), 0, stream>>>(text, vWqkv+(size_t)EE*EE, vbqkv+EE, nullptr,
                                                        wsK, nullptr, wsVt, NB*SEQ, 2*EE, EE);
  attn_k<<<dim3(PP/64, HH, NB), dim3(256), 0, stream>>>(wsQ, wsK, wsVt);
  gemm_bt<1,0,1><<<dim3(256,6), dim3(256), 0, stream>>>(wsQ, vWo, vbo, visual,
                                                        wsG, nullptr, nullptr, NB*PP, EE, EE);
  k_ln<<<dim3(NB*PP), dim3(256), 0, stream>>>(wsG, normg, normb);
  gemm_bt<3,0,1><<<dim3(256,6), dim3(256), 0, stream>>>(wsG, outW, outb, nullptr,
                                                        nullptr, outGO, nullptr, NB*PP, EE, EE);

  // per-class guidance
  k_class<<<dim3(NB*NCC), dim3(256), 0, stream>>>(wsUpd, wsScores, wsSent,
                                                  cW1, cb1, clng, clnb, cW2, cb2,
                                                  gfW1, gfb1, gflng, gflnb, gfW2, gfb2, outCG);
}

// Round 4
// 971.149 us; speedup vs baseline: 1.3413x; 1.3413x over previous
//
#include <hip/hip_runtime.h>
#include <stdint.h>

typedef unsigned short u16;
typedef __attribute__((ext_vector_type(8))) short short8;
typedef __attribute__((ext_vector_type(4))) float f32x4;

#define NB 32
#define PP 1024
#define SEQ 128
#define EE 768
#define HH 8
#define DD 96
#define NCC 5
#define NLL 3

__device__ __forceinline__ float bf2f(u16 x){ unsigned u=((unsigned)x)<<16; float f; __builtin_memcpy(&f,&u,4); return f; }
__device__ __forceinline__ u16 f2bf(float f){ unsigned u; __builtin_memcpy(&u,&f,4); u=(u+0x7FFFu+((u>>16)&1u))>>16; return (u16)u; }

__device__ __forceinline__ short8 cvt8(const float* p) {
  f32x4 a = *(const f32x4*)p;
  f32x4 b = *(const f32x4*)(p+4);
  short8 r;
  r[0]=(short)f2bf(a[0]); r[1]=(short)f2bf(a[1]); r[2]=(short)f2bf(a[2]); r[3]=(short)f2bf(a[3]);
  r[4]=(short)f2bf(b[0]); r[5]=(short)f2bf(b[1]); r[6]=(short)f2bf(b[2]); r[7]=(short)f2bf(b[3]);
  return r;
}

// ---------------- block LN stats helper (256 threads, 3 vals/thread) --------
__device__ __forceinline__ void ln_stats(float v0, float v1, float v2, float* red, int t,
                                         float& mean, float& rstd) {
  float ps = v0+v1+v2;
  float ps2 = v0*v0+v1*v1+v2*v2;
  #pragma unroll
  for (int o=32;o;o>>=1){ ps += __shfl_down(ps,o,64); ps2 += __shfl_down(ps2,o,64); }
  if ((t&63)==0){ red[t>>6]=ps; red[4+(t>>6)]=ps2; }
  __syncthreads();
  mean = (red[0]+red[1]+red[2]+red[3])*(1.0f/EE);
  float var = (red[4]+red[5]+red[6]+red[7])*(1.0f/EE) - mean*mean;
  rstd = rsqrtf(var + 1e-5f);
  __syncthreads();
}

// ---------------- big GEMM: C[m,n] = sum_k A[m,k]*B[n,k] + bias[n] ----------
#define BMT 128
#define BNT 128
#define LDK 40

template<int EPI, int AF, int BF>
__global__ __launch_bounds__(256) void gemm_bt(const void* __restrict__ Av, const void* __restrict__ Bv,
        const float* __restrict__ bias, const float* __restrict__ Res,
        u16* __restrict__ C, float* __restrict__ Cf, u16* __restrict__ C2, int M, int N, int K)
{
  __shared__ u16 As[BMT*LDK];
  __shared__ u16 Bs[BNT*LDK];
  const int m0 = blockIdx.x*BMT, n0 = blockIdx.y*BNT;
  const int t = threadIdx.x;
  const int l = t&63, w = t>>6, wr = w>>1, wc = w&1, lm = l&15, lg = l>>4;
  const int srow = t>>1, scol = (t&1)*16;
  f32x4 acc[4][4] = {};
  for (int k0=0; k0<K; k0+=32) {
    short8 a0,a1,b0,b1;
    if constexpr (AF) {
      const float* p = (const float*)Av + (size_t)(m0+srow)*K + scol + k0;
      a0 = cvt8(p); a1 = cvt8(p+8);
    } else {
      const u16* p = (const u16*)Av + (size_t)(m0+srow)*K + scol + k0;
      a0 = *(const short8*)p; a1 = *(const short8*)(p+8);
    }
    if constexpr (BF) {
      const float* p = (const float*)Bv + (size_t)(n0+srow)*K + scol + k0;
      b0 = cvt8(p); b1 = cvt8(p+8);
    } else {
      const u16* p = (const u16*)Bv + (size_t)(n0+srow)*K + scol + k0;
      b0 = *(const short8*)p; b1 = *(const short8*)(p+8);
    }
    __syncthreads();
    *(short8*)&As[srow*LDK+scol]   = a0;
    *(short8*)&As[srow*LDK+scol+8] = a1;
    *(short8*)&Bs[srow*LDK+scol]   = b0;
    *(short8*)&Bs[srow*LDK+scol+8] = b1;
    __syncthreads();
    short8 af[4], bfv[4];
    #pragma unroll
    for (int mi=0;mi<4;mi++) af[mi]  = *(const short8*)&As[(wr*64+mi*16+lm)*LDK + lg*8];
    #pragma unroll
    for (int ni=0;ni<4;ni++) bfv[ni] = *(const short8*)&Bs[(wc*64+ni*16+lm)*LDK + lg*8];
    #pragma unroll
    for (int mi=0;mi<4;mi++)
      #pragma unroll
      for (int ni=0;ni<4;ni++)
        acc[mi][ni] = __builtin_amdgcn_mfma_f32_16x16x32_bf16(af[mi], bfv[ni], acc[mi][ni], 0,0,0);
  }
  #pragma unroll
  for (int mi=0;mi<4;mi++) {
    #pragma unroll
    for (int ni=0;ni<4;ni++) {
      const int col = n0 + wc*64 + ni*16 + lm;
      const float bv = bias[col];
      #pragma unroll
      for (int r=0;r<4;r++) {
        const int row = m0 + wr*64 + mi*16 + lg*4 + r;
        float v = acc[mi][ni][r] + bv;
        if constexpr (EPI==1) v += Res[(size_t)row*N + col];
        if constexpr (EPI==3) {
          Cf[(size_t)row*N + col] = v;
        } else if constexpr (EPI==2) {
          if (col < EE) C[(size_t)row*EE + col] = f2bf(v);
          else C2[((size_t)(row>>7)*EE + (col-EE))*SEQ + (row&127)] = f2bf(v);
        } else {
          C[(size_t)row*N + col] = f2bf(v);
        }
      }
    }
  }
}

// ---------------- skinny MFMA GEMM: out[g] = A[g] @ W[g]^T + bias[g] --------
// MT rows (MT in {16,32,160}), N-tile 128 (grid.x), group = grid.y.
// A bf16 [*, lda]; W f32 [768, K] per group (converted to bf16 during staging).
// EPI bit0: f32 store to Cf; bit1: bf16 store to Cb.
template<int MT, int EPI>
__global__ __launch_bounds__(256) void gemm_skinny(
    const u16* __restrict__ A, const float* __restrict__ W,
    const float* __restrict__ bias,
    float* __restrict__ Cf, u16* __restrict__ Cb,
    int Mreal, int K, int lda,
    long strideA, long strideW, long strideB,
    int ldoF, long strideOF, int ldoB, long strideOB)
{
  __shared__ u16 As[MT*LDK];
  __shared__ u16 Ws[128*LDK];
  const int g = blockIdx.y;
  const int n0 = blockIdx.x*128;
  const int t = threadIdx.x;
  const int l = t&63, w = t>>6, lm = l&15, lg = l>>4;
  A += (size_t)g*strideA; W += (size_t)g*strideW; bias += (size_t)g*strideB;
  constexpr int AIT = (MT*32 + 2047)/2048;
  f32x4 acc[MT/16][2] = {};
  for (int k0=0; k0<K; k0+=32) {
    short8 areg[AIT];
    #pragma unroll
    for (int it=0; it<AIT; ++it) {
      const int idx = it*2048 + t*8;
      if (idx < MT*32) {
        const int row = idx >> 5, col = idx & 31;
        if (row < Mreal) areg[it] = *(const short8*)(A + (size_t)row*lda + k0 + col);
        else { short8 z = {0,0,0,0,0,0,0,0}; areg[it] = z; }
      }
    }
    const float* wp = W + (size_t)(n0 + (t>>1))*K + k0 + (t&1)*16;
    short8 w0 = cvt8(wp), w1 = cvt8(wp+8);
    __syncthreads();
    #pragma unroll
    for (int it=0; it<AIT; ++it) {
      const int idx = it*2048 + t*8;
      if (idx < MT*32) {
        const int row = idx >> 5, col = idx & 31;
        *(short8*)&As[row*LDK + col] = areg[it];
      }
    }
    *(short8*)&Ws[(t>>1)*LDK + (t&1)*16]     = w0;
    *(short8*)&Ws[(t>>1)*LDK + (t&1)*16 + 8] = w1;
    __syncthreads();
    const short8 bf0 = *(const short8*)&Ws[(w*32 + lm)*LDK + lg*8];
    const short8 bf1 = *(const short8*)&Ws[(w*32 + 16 + lm)*LDK + lg*8];
    #pragma unroll
    for (int m=0;m<MT/16;m++) {
      const short8 af = *(const short8*)&As[(m*16+lm)*LDK + lg*8];
      acc[m][0] = __builtin_amdgcn_mfma_f32_16x16x32_bf16(af, bf0, acc[m][0], 0,0,0);
      acc[m][1] = __builtin_amdgcn_mfma_f32_16x16x32_bf16(af, bf1, acc[m][1], 0,0,0);
    }
  }
  #pragma unroll
  for (int ni=0;ni<2;ni++) {
    const int col = n0 + w*32 + ni*16 + lm;
    const float bv = bias[col];
    #pragma unroll
    for (int m=0;m<MT/16;m++) {
      #pragma unroll
      for (int r=0;r<4;r++) {
        const int row = m*16 + lg*4 + r;
        if (row < Mreal) {
          const float v = acc[m][ni][r] + bv;
          if constexpr (EPI & 1) Cf[(size_t)g*strideOF + (size_t)row*ldoF + col] = v;
          if constexpr (EPI & 2) Cb[(size_t)g*strideOB + (size_t)row*ldoB + col] = f2bf(v);
        }
      }
    }
  }
}

// ---------------- LN + relu, f32 in -> bf16 out, per-row, grouped params ----
__global__ __launch_bounds__(256) void k_lnrelu(const float* __restrict__ in, u16* __restrict__ out,
    const float* __restrict__ gamma, const float* __restrict__ beta, int rpg)
{
  const int row = blockIdx.x, t = threadIdx.x;
  const float* p = in + (size_t)row*EE;
  const float* gm = gamma + (size_t)(row/rpg)*EE;
  const float* bt = beta  + (size_t)(row/rpg)*EE;
  __shared__ float red[8];
  float v[3];
  #pragma unroll
  for (int i=0;i<3;i++) v[i]=p[t+i*256];
  float mean, rstd;
  ln_stats(v[0],v[1],v[2], red, t, mean, rstd);
  #pragma unroll
  for (int i=0;i<3;i++) {
    const int e=t+i*256;
    out[(size_t)row*EE+e]=f2bf(fmaxf((v[i]-mean)*rstd*gm[e]+bt[e],0.f));
  }
}

// ---------------- graph: adjacency/edge combine -> comb bf16 [15][1536] ----
__global__ __launch_bounds__(256) void k_comb(const float* __restrict__ node_all,
    const float* __restrict__ edge_all, u16* __restrict__ comb)
{
  const int lc = blockIdx.x, ll = lc/NCC, c = lc%NCC, t = threadIdx.x;
  const float* node = node_all + (size_t)ll*NCC*EE;
  const float* edge = edge_all + (size_t)ll*3*EE;
  #pragma unroll
  for (int i=0;i<3;i++) {
    const int e = t + i*256;
    float n0=node[e], n1=node[EE+e], n2=node[2*EE+e], n3=node[3*EE+e];
    float nc_=node[(size_t)c*EE+e];
    float e0=edge[e], e1=edge[EE+e], e2=edge[2*EE+e];
    float s0;
    if (c==0) s0=n1+n2; else if (c==1) s0=n0+n2; else if (c==2) s0=n0+n1+n3; else if (c==3) s0=n2; else s0=0.f;
    float ef = (s0*e0 + ((c==3)? n2*e1 : 0.f) + nc_*e2)*(1.0f/3.0f);
    comb[(size_t)lc*2*EE + e]      = f2bf(nc_);
    comb[(size_t)lc*2*EE + EE + e] = f2bf(ef);
  }
}

__global__ __launch_bounds__(256) void k_sent_init(const float* __restrict__ se, float* __restrict__ sent) {
  const int i = blockIdx.x*256 + threadIdx.x;
  if (i < NB*EE) sent[i] = se[i];
}

// ---------------- graph: per-batch attention + sent update (sequential in l) -
__global__ __launch_bounds__(256) void k_attn(int l, const float* __restrict__ Wqkva, const float* __restrict__ bqkva,
    const float* __restrict__ presence, const float* __restrict__ upd, const float* __restrict__ khg,
    float* __restrict__ sent, float* __restrict__ sc_ws, float* __restrict__ out_scores)
{
  const int b = blockIdx.x, t = threadIdx.x;
  __shared__ float sbuf[EE];
  __shared__ float qh[EE];
  __shared__ float scl[HH][NCC];
  __shared__ float wsc[NCC];
  __shared__ float scr[NCC];
  #pragma unroll
  for (int i=0;i<3;i++){ const int e=t+i*256; sbuf[e]=sent[(size_t)b*EE+e]; }
  __syncthreads();
  const float* Wq = Wqkva + (size_t)l*3*EE*EE;
  const float* bq = bqkva + (size_t)l*3*EE;
  #pragma unroll
  for (int i=0;i<3;i++) {
    const int j=t+i*256;
    const float* wrow = Wq + (size_t)j*EE;
    float a = bq[j];
    for (int k=0;k<EE;k+=4) {
      f32x4 w4 = *(const f32x4*)(wrow+k);
      a += sbuf[k]*w4[0]+sbuf[k+1]*w4[1]+sbuf[k+2]*w4[2]+sbuf[k+3]*w4[3];
    }
    qh[j]=a;
  }
  __syncthreads();
  if (t < HH*NCC) {
    const int hh=t/NCC, cc=t%NCC;
    const float* kr = khg + (size_t)(l*NCC+cc)*EE + hh*DD;
    float a=0.f;
    #pragma unroll 8
    for (int d=0;d<DD;d++) a += qh[hh*DD+d]*kr[d];
    scl[hh][cc]=a*0.1020620726159658f;
  }
  __syncthreads();
  if (t < HH) {
    float m=scl[t][0];
    #pragma unroll
    for (int c2=1;c2<NCC;c2++) m=fmaxf(m,scl[t][c2]);
    float ex[NCC]; float s=0.f;
    #pragma unroll
    for (int c2=0;c2<NCC;c2++){ ex[c2]=__expf(scl[t][c2]-m); s+=ex[c2]; }
    #pragma unroll
    for (int c2=0;c2<NCC;c2++) scl[t][c2]=ex[c2]/s;
  }
  __syncthreads();
  if (t < NCC) {
    float wv=0.f;
    #pragma unroll
    for (int hh=0;hh<HH;hh++) wv += scl[hh][t];
    wv *= (1.0f/HH);
    wsc[t] = wv*(presence[b*NCC+t]+0.1f);
  }
  __syncthreads();
  if (t==0) {
    float m=wsc[0];
    #pragma unroll
    for (int c2=1;c2<NCC;c2++) m=fmaxf(m,wsc[c2]);
    float ex[NCC]; float s=0.f;
    #pragma unroll
    for (int c2=0;c2<NCC;c2++){ ex[c2]=__expf(wsc[c2]-m); s+=ex[c2]; }
    #pragma unroll
    for (int c2=0;c2<NCC;c2++){
      float v=ex[c2]/s; scr[c2]=v; sc_ws[b*NCC+c2]=v;
      if (out_scores) out_scores[b*NCC+c2]=v;
    }
  }
  __syncthreads();
  #pragma unroll
  for (int i=0;i<3;i++) {
    const int e=t+i*256;
    float a=0.f;
    #pragma unroll
    for (int c2=0;c2<NCC;c2++) a += scr[c2]*upd[(size_t)(l*NCC+c2)*EE+e];
    sent[(size_t)b*EE+e] = sbuf[e] + a*(1.0f/NCC);
  }
}

// ---------------- act prep: actB[c][b][e] bf16, cat sent half ---------------
__global__ __launch_bounds__(256) void k_actprep(const float* __restrict__ upd, const float* __restrict__ sc_ws,
    const float* __restrict__ sent, u16* __restrict__ actB, u16* __restrict__ cat)
{
  const int bid = blockIdx.x, c = bid/NB, b = bid%NB, t = threadIdx.x;
  const float sc = sc_ws[b*NCC+c];
  #pragma unroll
  for (int i=0;i<3;i++) {
    const int e = t + i*256;
    actB[((size_t)c*NB + b)*EE + e] = f2bf(upd[(size_t)(2*NCC+c)*EE + e]*sc);
    cat[((size_t)(b*NCC+c))*2*EE + EE + e] = f2bf(sent[(size_t)b*EE + e]);
  }
}

// ---------------- fused attention: per (b, h, 64-row q-tile) ----------------
__global__ __launch_bounds__(256) void attn_k(u16* __restrict__ Q, const u16* __restrict__ Kb,
                                              const u16* __restrict__ Vt)
{
  const int qt = blockIdx.x, h = blockIdx.y, b = blockIdx.z;
  const int t = threadIdx.x, l = t&63, w = t>>6, wr = w>>1, wc = w&1, lm = l&15, lg = l>>4;
  __shared__ u16 Ps[64][136];
  __shared__ float redm[2][64];
  __shared__ float reds[2][64];
  u16* qb = Q + ((size_t)(b*PP + qt*64))*EE + h*DD;
  const u16* kb = Kb + ((size_t)b*SEQ)*EE + h*DD;
  const u16* vb = Vt + ((size_t)(b*HH+h))*DD*SEQ;

  f32x4 acc[2][4] = {};
  #pragma unroll
  for (int kc=0;kc<3;kc++) {
    short8 af[2], bv[4];
    #pragma unroll
    for (int mi=0;mi<2;mi++) af[mi] = *(const short8*)(qb + (size_t)(wr*32+mi*16+lm)*EE + kc*32 + lg*8);
    #pragma unroll
    for (int ni=0;ni<4;ni++) bv[ni] = *(const short8*)(kb + (size_t)(wc*64+ni*16+lm)*EE + kc*32 + lg*8);
    #pragma unroll
    for (int mi=0;mi<2;mi++)
      #pragma unroll
      for (int ni=0;ni<4;ni++)
        acc[mi][ni] = __builtin_amdgcn_mfma_f32_16x16x32_bf16(af[mi], bv[ni], acc[mi][ni], 0,0,0);
  }
  const float scale = 0.1020620726159658f; // 1/sqrt(96)
  float gmax[2][4], gsum[2][4];
  #pragma unroll
  for (int mi=0;mi<2;mi++)
    #pragma unroll
    for (int r=0;r<4;r++) {
      float v = fmaxf(fmaxf(acc[mi][0][r],acc[mi][1][r]),fmaxf(acc[mi][2][r],acc[mi][3][r]));
      #pragma unroll
      for (int mk=1;mk<16;mk<<=1) v = fmaxf(v, __shfl_xor(v,mk,64));
      gmax[mi][r]=v;
    }
  if (lm==0) {
    #pragma unroll
    for (int mi=0;mi<2;mi++)
      #pragma unroll
      for (int r=0;r<4;r++) redm[wc][wr*32+mi*16+lg*4+r] = gmax[mi][r];
  }
  __syncthreads();
  #pragma unroll
  for (int mi=0;mi<2;mi++)
    #pragma unroll
    for (int r=0;r<4;r++) {
      const int row = wr*32+mi*16+lg*4+r;
      gmax[mi][r] = fmaxf(redm[0][row], redm[1][row]);
    }
  #pragma unroll
  for (int mi=0;mi<2;mi++)
    #pragma unroll
    for (int r=0;r<4;r++) {
      float s=0.f;
      #pragma unroll
      for (int ni=0;ni<4;ni++) {
        float p = __expf((acc[mi][ni][r]-gmax[mi][r])*scale);
        acc[mi][ni][r]=p; s+=p;
      }
      #pragma unroll
      for (int mk=1;mk<16;mk<<=1) s += __shfl_xor(s,mk,64);
      gsum[mi][r]=s;
    }
  __syncthreads();
  if (lm==0) {
    #pragma unroll
    for (int mi=0;mi<2;mi++)
      #pragma unroll
      for (int r=0;r<4;r++) reds[wc][wr*32+mi*16+lg*4+r] = gsum[mi][r];
  }
  __syncthreads();
  #pragma unroll
  for (int mi=0;mi<2;mi++)
    #pragma unroll
    for (int r=0;r<4;r++) {
      const int row = wr*32+mi*16+lg*4+r;
      const float inv = 1.0f/(reds[0][row]+reds[1][row]);
      #pragma unroll
      for (int ni=0;ni<4;ni++)
        Ps[row][wc*64+ni*16+lm] = f2bf(acc[mi][ni][r]*inv);
    }
  __syncthreads();

  f32x4 oacc[2][3] = {};
  #pragma unroll
  for (int kc=0;kc<4;kc++) {
    short8 pa[2], vv[3];
    #pragma unroll
    for (int mi=0;mi<2;mi++) pa[mi] = *(const short8*)&Ps[wr*32+mi*16+lm][kc*32+lg*8];
    #pragma unroll
    for (int ni=0;ni<3;ni++) vv[ni] = *(const short8*)(vb + (size_t)(wc*48+ni*16+lm)*SEQ + kc*32 + lg*8);
    #pragma unroll
    for (int mi=0;mi<2;mi++)
      #pragma unroll
      for (int ni=0;ni<3;ni++)
        oacc[mi][ni] = __builtin_amdgcn_mfma_f32_16x16x32_bf16(pa[mi], vv[ni], oacc[mi][ni], 0,0,0);
  }
  #pragma unroll
  for (int mi=0;mi<2;mi++)
    #pragma unroll
    for (int ni=0;ni<3;ni++)
      #pragma unroll
      for (int r=0;r<4;r++)
        qb[(size_t)(wr*32+mi*16+lg*4+r)*EE + wc*48+ni*16+lm] = f2bf(oacc[mi][ni][r]);
}

// ---------------- row LayerNorm in-place (bf16 data, f32 params) -------------
__global__ __launch_bounds__(256) void k_ln(u16* __restrict__ G, const float* __restrict__ gw, const float* __restrict__ gb)
{
  const int row = blockIdx.x, t = threadIdx.x;
  u16* p = G + (size_t)row*EE;
  __shared__ float red[8];
  float v[3];
  #pragma unroll
  for (int i=0;i<3;i++) v[i]=bf2f(p[t+i*256]);
  float mean, rstd;
  ln_stats(v[0],v[1],v[2], red, t, mean, rstd);
  #pragma unroll
  for (int i=0;i<3;i++) {
    const int e=t+i*256;
    p[e]=f2bf((v[i]-mean)*rstd*gw[e]+gb[e]);
  }
}

// ---------------- host launch ------------------------------------------------
extern "C" void kernel_launch(void* const* d_in, const int* in_sizes, int n_in,
                              void* d_out, int out_size, void* d_ws, size_t ws_size,
                              hipStream_t stream)
{
  const float* visual   = (const float*)d_in[0];
  const float* text     = (const float*)d_in[1];
  const float* sentemb  = (const float*)d_in[2];
  const float* presence = (const float*)d_in[3];
  const float* gnode = (const float*)d_in[4];
  const float* gedge = (const float*)d_in[5];
  const float* gWqkv = (const float*)d_in[6];
  const float* gbqkv = (const float*)d_in[7];
  const float* gW1 = (const float*)d_in[10];
  const float* gb1 = (const float*)d_in[11];
  const float* glng = (const float*)d_in[12];
  const float* glnb = (const float*)d_in[13];
  const float* gW2 = (const float*)d_in[14];
  const float* gb2 = (const float*)d_in[15];
  const float* vWqkv = (const float*)d_in[16];
  const float* vbqkv = (const float*)d_in[17];
  const float* vWo = (const float*)d_in[18];
  const float* vbo = (const float*)d_in[19];
  const float* cW1 = (const float*)d_in[20];
  const float* cb1 = (const float*)d_in[21];
  const float* clng = (const float*)d_in[22];
  const float* clnb = (const float*)d_in[23];
  const float* cW2 = (const float*)d_in[24];
  const float* cb2 = (const float*)d_in[25];
  const float* gfW1 = (const float*)d_in[26];
  const float* gfb1 = (const float*)d_in[27];
  const float* gflng = (const float*)d_in[28];
  const float* gflnb = (const float*)d_in[29];
  const float* gfW2 = (const float*)d_in[30];
  const float* gfb2 = (const float*)d_in[31];
  const float* outW = (const float*)d_in[32];
  const float* outb = (const float*)d_in[33];
  const float* normg = (const float*)d_in[34];
  const float* normb = (const float*)d_in[35];

  char* ws = (char*)d_ws;
  u16* wsQ  = (u16*)(ws);                     // 32768x768 bf16 (Q, then attn out in-place)
  u16* wsK  = (u16*)(ws + 50331648);          // 4096x768 bf16   (fusion phase)
  u16* wsVt = (u16*)(ws + 56623104);          // (32*8*96)x128 bf16 (fusion phase)
  u16* wsG  = (u16*)(ws + 62914560);          // 32768x768 bf16 (pre-LN / grounded)

  // graph/class scratch overlays the wsK/wsVt region (dead until fusion phase;
  // stream is serial so reuse is safe).
  char* P = ws + 50331648;
  float* wsSent   = (float*)(P);              // 32x768 f32
  float* wsUpd    = (float*)(P +   98304);    // 15x768 f32
  float* wsKhg    = (float*)(P +  144384);    // 15x768 f32
  float* wsScores = (float*)(P +  190464);    // 160 f32
  u16*   wsComb   = (u16*)  (P +  191104);    // 15x1536 bf16
  float* wsH      = (float*)(P +  237184);    // 15x768 f32
  u16*   wsHb     = (u16*)  (P +  283264);    // 15x768 bf16
  u16*   wsUpdB   = (u16*)  (P +  306304);    // 15x768 bf16
  u16*   wsActB   = (u16*)  (P +  329344);    // 5x32x768 bf16
  float* wsH1     = (float*)(P +  575104);    // 160x768 f32 ([c][b] order)
  u16*   wsH1b    = (u16*)  (P + 1066624);    // 160x768 bf16
  u16*   wsCat    = (u16*)  (P + 1312384);    // 160x1536 bf16 ([b*5+c] order)
  float* wsG1     = (float*)(P + 1803904);    // 160x768 f32
  u16*   wsG1b    = (u16*)  (P + 2295424);    // 160x768 bf16

  float* outGO = (float*)d_out;
  float* outCG = outGO + 25165824;
  float* outSC = outGO + 25288704;

  // ---- graph node-update chain (batch-independent, all layers) ----
  k_comb<<<dim3(NLL*NCC), dim3(256), 0, stream>>>(gnode, gedge, wsComb);
  gemm_skinny<16,1><<<dim3(6,NLL), dim3(256), 0, stream>>>(wsComb, gW1, gb1, wsH, nullptr,
      NCC, 2*EE, 2*EE, (long)NCC*2*EE, (long)EE*2*EE, (long)EE, EE, (long)NCC*EE, 0, 0);
  k_lnrelu<<<dim3(NLL*NCC), dim3(256), 0, stream>>>(wsH, wsHb, glng, glnb, NCC);
  gemm_skinny<16,3><<<dim3(6,NLL), dim3(256), 0, stream>>>(wsHb, gW2, gb2, wsUpd, wsUpdB,
      NCC, EE, EE, (long)NCC*EE, (long)EE*EE, (long)EE, EE, (long)NCC*EE, EE, (long)NCC*EE);
  gemm_skinny<16,1><<<dim3(6,NLL), dim3(256), 0, stream>>>(wsUpdB, gWqkv + (size_t)EE*EE, gbqkv + EE, wsKhg, nullptr,
      NCC, EE, EE, (long)NCC*EE, (long)3*EE*EE, (long)3*EE, EE, (long)NCC*EE, 0, 0);

  // ---- sentence loop ----
  k_sent_init<<<dim3(96), dim3(256), 0, stream>>>(sentemb, wsSent);
  for (int l=0;l<NLL;l++)
    k_attn<<<dim3(NB), dim3(256), 0, stream>>>(l, gWqkv, gbqkv, presence, wsUpd, wsKhg,
                                               wsSent, wsScores, (l==NLL-1)?outSC:(float*)nullptr);

  // ---- class guidance chain (class-major skinny GEMMs) ----
  k_actprep<<<dim3(NCC*NB), dim3(256), 0, stream>>>(wsUpd, wsScores, wsSent, wsActB, wsCat);
  gemm_skinny<32,1><<<dim3(6,NCC), dim3(256), 0, stream>>>(wsActB, cW1, cb1, wsH1, nullptr,
      NB, EE, EE, (long)NB*EE, (long)EE*EE, (long)EE, EE, (long)NB*EE, 0, 0);
  k_lnrelu<<<dim3(NCC*NB), dim3(256), 0, stream>>>(wsH1, wsH1b, clng, clnb, NB);
  gemm_skinny<32,2><<<dim3(6,NCC), dim3(256), 0, stream>>>(wsH1b, cW2, cb2, nullptr, wsCat,
      NB, EE, EE, (long)NB*EE, (long)EE*EE, (long)EE, 0, 0, NCC*2*EE, (long)2*EE);
  gemm_skinny<160,1><<<dim3(6,1), dim3(256), 0, stream>>>(wsCat, gfW1, gfb1, wsG1, nullptr,
      NB*NCC, 2*EE, 2*EE, 0, 0, 0, EE, 0, 0, 0);
  k_lnrelu<<<dim3(NB*NCC), dim3(256), 0, stream>>>(wsG1, wsG1b, gflng, gflnb, NB*NCC);
  gemm_skinny<160,1><<<dim3(6,1), dim3(256), 0, stream>>>(wsG1b, gfW2, gfb2, outCG, nullptr,
      NB*NCC, EE, EE, 0, 0, 0, EE, 0, 0, 0);

  // ---- visual-text fusion (uses wsK/wsVt region AFTER class chain done) ----
  gemm_bt<0,1,1><<<dim3(256,6), dim3(256), 0, stream>>>(visual, vWqkv, vbqkv, nullptr,
                                                        wsQ, nullptr, nullptr, NB*PP, EE, EE);
  gemm_bt<2,1,1><<<dim3(32,12), dim3(256), 0, stream>>>(text, vWqkv+(size_t)EE*EE, vbqkv+EE, nullptr,
                                                        wsK, nullptr, wsVt, NB*SEQ, 2*EE, EE);
  attn_k<<<dim3(PP/64, HH, NB), dim3(256), 0, stream>>>(wsQ, wsK, wsVt);
  gemm_bt<1,0,1><<<dim3(256,6), dim3(256), 0, stream>>>(wsQ, vWo, vbo, visual,
                                                        wsG, nullptr, nullptr, NB*PP, EE, EE);
  k_ln<<<dim3(NB*PP), dim3(256), 0, stream>>>(wsG, normg, normb);
  gemm_bt<3,0,1><<<dim3(256,6), dim3(256), 0, stream>>>(wsG, outW, outb, nullptr,
                                                        nullptr, outGO, nullptr, NB*PP, EE, EE);
}

// Round 5
// 762.874 us; speedup vs baseline: 1.7074x; 1.2730x over previous
//
#include <hip/hip_runtime.h>
#include <stdint.h>

typedef unsigned short u16;
typedef __attribute__((ext_vector_type(8))) short short8;
typedef __attribute__((ext_vector_type(4))) float f32x4;

#define NB 32
#define PP 1024
#define SEQ 128
#define EE 768
#define HH 8
#define DD 96
#define NCC 5
#define NLL 3

__device__ __forceinline__ float bf2f(u16 x){ unsigned u=((unsigned)x)<<16; float f; __builtin_memcpy(&f,&u,4); return f; }
__device__ __forceinline__ u16 f2bf(float f){ unsigned u; __builtin_memcpy(&u,&f,4); u=(u+0x7FFFu+((u>>16)&1u))>>16; return (u16)u; }

__device__ __forceinline__ short8 cvt8(const float* p) {
  f32x4 a = *(const f32x4*)p;
  f32x4 b = *(const f32x4*)(p+4);
  short8 r;
  r[0]=(short)f2bf(a[0]); r[1]=(short)f2bf(a[1]); r[2]=(short)f2bf(a[2]); r[3]=(short)f2bf(a[3]);
  r[4]=(short)f2bf(b[0]); r[5]=(short)f2bf(b[1]); r[6]=(short)f2bf(b[2]); r[7]=(short)f2bf(b[3]);
  return r;
}

__device__ __forceinline__ void gl16(const u16* g, u16* l) {
  __builtin_amdgcn_global_load_lds((const __attribute__((address_space(1))) void*)g,
                                   (__attribute__((address_space(3))) void*)l, 16, 0, 0);
}

// ---------------- f32 -> bf16 bulk convert ----------------------------------
__global__ __launch_bounds__(256) void k_cvt(const float* __restrict__ s, u16* __restrict__ d, int n8) {
  int i = blockIdx.x*256 + threadIdx.x;
  const int stride = gridDim.x*256;
  for (; i < n8; i += stride) *(short8*)(d + (size_t)i*8) = cvt8(s + (size_t)i*8);
}

// ---------------- block LN stats helper (256 threads, 3 vals/thread) --------
__device__ __forceinline__ void ln_stats(float v0, float v1, float v2, float* red, int t,
                                         float& mean, float& rstd) {
  float ps = v0+v1+v2;
  float ps2 = v0*v0+v1*v1+v2*v2;
  #pragma unroll
  for (int o=32;o;o>>=1){ ps += __shfl_down(ps,o,64); ps2 += __shfl_down(ps2,o,64); }
  if ((t&63)==0){ red[t>>6]=ps; red[4+(t>>6)]=ps2; }
  __syncthreads();
  mean = (red[0]+red[1]+red[2]+red[3])*(1.0f/EE);
  float var = (red[4]+red[5]+red[6]+red[7])*(1.0f/EE) - mean*mean;
  rstd = rsqrtf(var + 1e-5f);
  __syncthreads();
}

// ---------------- big GEMM via global_load_lds + swizzle --------------------
// C[m,n] = sum_k A[m,k]*B[n,k] + bias[n]; all A/B bf16, K mult of 32, tiles 128x128.
// LDS layout: linear [64 B/row]; source pre-swizzle chunk^=((row>>1)&3) pairs with
// read-side byte = row*64 + ((lg^((row>>1)&3))<<4)  (both-sides involution).
// EPI 0: bf16 C. EPI 1: bf16 C + bf16 residual. EPI 2: KV split. EPI 3: f32 Cf.
template<int EPI>
__global__ __launch_bounds__(256) void gemm_bt(const u16* __restrict__ A, const u16* __restrict__ Bw,
        const float* __restrict__ bias, const u16* __restrict__ Res,
        u16* __restrict__ C, float* __restrict__ Cf, u16* __restrict__ C2, int M, int N, int K)
{
  __shared__ u16 As[2][4096];
  __shared__ u16 Bs[2][4096];
  const int m0 = blockIdx.x*128, n0 = blockIdx.y*128;
  const int t = threadIdx.x;
  const int lane = t&63, w = t>>6, wr = w>>1, wc = w&1, lm = lane&15, lg = lane>>4;
  // staging: linear LDS byte o = w*1024 + lane*16 (+4096 for chunk 1)
  const int o   = w*1024 + lane*16;
  const int srow = o>>6;
  const int sg   = ((o>>4)&3) ^ ((srow>>1)&3);
  const u16* ag = A  + (size_t)(m0+srow)*K + sg*8;
  const u16* bg = Bw + (size_t)(n0+srow)*K + sg*8;
  const size_t rstep = (size_t)64*K;       // chunk1: row+64, same swizzle
  // read-side bases (u16 elements)
  const int s  = (lm>>1)&3;
  const int ra = (wr*64+lm)*32 + (lg^s)*8;
  const int rb = (wc*64+lm)*32 + (lg^s)*8;

  f32x4 acc[4][4] = {};
  gl16(ag,         &As[0][w*512]);
  gl16(ag + rstep, &As[0][2048 + w*512]);
  gl16(bg,         &Bs[0][w*512]);
  gl16(bg + rstep, &Bs[0][2048 + w*512]);
  __syncthreads();
  int cur = 0;
  const int NT = K>>5;
  for (int kt=0; kt<NT; ++kt) {
    if (kt+1 < NT) {
      const int k0 = (kt+1)<<5;
      gl16(ag + k0,         &As[cur^1][w*512]);
      gl16(ag + k0 + rstep, &As[cur^1][2048 + w*512]);
      gl16(bg + k0,         &Bs[cur^1][w*512]);
      gl16(bg + k0 + rstep, &Bs[cur^1][2048 + w*512]);
    }
    short8 af[4], bf[4];
    #pragma unroll
    for (int mi=0;mi<4;mi++) af[mi] = *(const short8*)&As[cur][ra + mi*512];
    #pragma unroll
    for (int ni=0;ni<4;ni++) bf[ni] = *(const short8*)&Bs[cur][rb + ni*512];
    #pragma unroll
    for (int mi=0;mi<4;mi++)
      #pragma unroll
      for (int ni=0;ni<4;ni++)
        acc[mi][ni] = __builtin_amdgcn_mfma_f32_16x16x32_bf16(af[mi], bf[ni], acc[mi][ni], 0,0,0);
    __syncthreads();
    cur ^= 1;
  }
  #pragma unroll
  for (int mi=0;mi<4;mi++) {
    #pragma unroll
    for (int ni=0;ni<4;ni++) {
      const int col = n0 + wc*64 + ni*16 + lm;
      const float bv = bias[col];
      #pragma unroll
      for (int r=0;r<4;r++) {
        const int row = m0 + wr*64 + mi*16 + lg*4 + r;
        float v = acc[mi][ni][r] + bv;
        if constexpr (EPI==1) v += bf2f(Res[(size_t)row*N + col]);
        if constexpr (EPI==3) {
          Cf[(size_t)row*N + col] = v;
        } else if constexpr (EPI==2) {
          if (col < EE) C[(size_t)row*EE + col] = f2bf(v);
          else C2[((size_t)(row>>7)*EE + (col-EE))*SEQ + (row&127)] = f2bf(v);
        } else {
          C[(size_t)row*N + col] = f2bf(v);
        }
      }
    }
  }
}

// ---------------- skinny MFMA GEMM: out[g] = A[g] @ W[g]^T + bias[g] --------
// MT in {16,32,160}; N-tile 128 (grid.x); group = grid.y. W f32 (cvt on stage).
// AF: A is f32 (cvt on stage) vs bf16. EPI bit0: f32 out; bit1: bf16 out.
#define LDK 40
template<int MT, int EPI, int AF>
__global__ __launch_bounds__(256) void gemm_skinny(
    const void* __restrict__ Av, const float* __restrict__ W,
    const float* __restrict__ bias,
    float* __restrict__ Cf, u16* __restrict__ Cb,
    int Mreal, int K, int lda,
    long strideA, long strideW, long strideB,
    int ldoF, long strideOF, int ldoB, long strideOB)
{
  __shared__ u16 As[MT*LDK];
  __shared__ u16 Ws[128*LDK];
  const int g = blockIdx.y;
  const int n0 = blockIdx.x*128;
  const int t = threadIdx.x;
  const int l = t&63, w = t>>6, lm = l&15, lg = l>>4;
  W += (size_t)g*strideW; bias += (size_t)g*strideB;
  constexpr int AIT = (MT*32 + 2047)/2048;
  f32x4 acc[MT/16][2] = {};
  for (int k0=0; k0<K; k0+=32) {
    short8 areg[AIT];
    #pragma unroll
    for (int it=0; it<AIT; ++it) {
      const int idx = it*2048 + t*8;
      if (idx < MT*32) {
        const int row = idx >> 5, col = idx & 31;
        if (row < Mreal) {
          if constexpr (AF) areg[it] = cvt8((const float*)Av + (size_t)g*strideA + (size_t)row*lda + k0 + col);
          else areg[it] = *(const short8*)((const u16*)Av + (size_t)g*strideA + (size_t)row*lda + k0 + col);
        } else { short8 z = {0,0,0,0,0,0,0,0}; areg[it] = z; }
      }
    }
    const float* wp = W + (size_t)(n0 + (t>>1))*K + k0 + (t&1)*16;
    short8 w0 = cvt8(wp), w1 = cvt8(wp+8);
    __syncthreads();
    #pragma unroll
    for (int it=0; it<AIT; ++it) {
      const int idx = it*2048 + t*8;
      if (idx < MT*32) {
        const int row = idx >> 5, col = idx & 31;
        *(short8*)&As[row*LDK + col] = areg[it];
      }
    }
    *(short8*)&Ws[(t>>1)*LDK + (t&1)*16]     = w0;
    *(short8*)&Ws[(t>>1)*LDK + (t&1)*16 + 8] = w1;
    __syncthreads();
    const short8 bf0 = *(const short8*)&Ws[(w*32 + lm)*LDK + lg*8];
    const short8 bf1 = *(const short8*)&Ws[(w*32 + 16 + lm)*LDK + lg*8];
    #pragma unroll
    for (int m=0;m<MT/16;m++) {
      const short8 af = *(const short8*)&As[(m*16+lm)*LDK + lg*8];
      acc[m][0] = __builtin_amdgcn_mfma_f32_16x16x32_bf16(af, bf0, acc[m][0], 0,0,0);
      acc[m][1] = __builtin_amdgcn_mfma_f32_16x16x32_bf16(af, bf1, acc[m][1], 0,0,0);
    }
    __syncthreads();
  }
  #pragma unroll
  for (int ni=0;ni<2;ni++) {
    const int col = n0 + w*32 + ni*16 + lm;
    const float bv = bias[col];
    #pragma unroll
    for (int m=0;m<MT/16;m++) {
      #pragma unroll
      for (int r=0;r<4;r++) {
        const int row = m*16 + lg*4 + r;
        if (row < Mreal) {
          const float v = acc[m][ni][r] + bv;
          if constexpr (EPI & 1) Cf[(size_t)g*strideOF + (size_t)row*ldoF + col] = v;
          if constexpr (EPI & 2) Cb[(size_t)g*strideOB + (size_t)row*ldoB + col] = f2bf(v);
        }
      }
    }
  }
}

// ---------------- LN + relu, f32 in -> bf16 out ------------------------------
__global__ __launch_bounds__(256) void k_lnrelu(const float* __restrict__ in, u16* __restrict__ out,
    const float* __restrict__ gamma, const float* __restrict__ beta, int rpg)
{
  const int row = blockIdx.x, t = threadIdx.x;
  const float* p = in + (size_t)row*EE;
  const float* gm = gamma + (size_t)(row/rpg)*EE;
  const float* bt = beta  + (size_t)(row/rpg)*EE;
  __shared__ float red[8];
  float v[3];
  #pragma unroll
  for (int i=0;i<3;i++) v[i]=p[t+i*256];
  float mean, rstd;
  ln_stats(v[0],v[1],v[2], red, t, mean, rstd);
  #pragma unroll
  for (int i=0;i<3;i++) {
    const int e=t+i*256;
    out[(size_t)row*EE+e]=f2bf(fmaxf((v[i]-mean)*rstd*gm[e]+bt[e],0.f));
  }
}

// ---------------- graph: adjacency/edge combine -> comb bf16 [15][1536] ----
__global__ __launch_bounds__(256) void k_comb(const float* __restrict__ node_all,
    const float* __restrict__ edge_all, u16* __restrict__ comb)
{
  const int lc = blockIdx.x, ll = lc/NCC, c = lc%NCC, t = threadIdx.x;
  const float* node = node_all + (size_t)ll*NCC*EE;
  const float* edge = edge_all + (size_t)ll*3*EE;
  #pragma unroll
  for (int i=0;i<3;i++) {
    const int e = t + i*256;
    float n0=node[e], n1=node[EE+e], n2=node[2*EE+e], n3=node[3*EE+e];
    float nc_=node[(size_t)c*EE+e];
    float e0=edge[e], e1=edge[EE+e], e2=edge[2*EE+e];
    float s0;
    if (c==0) s0=n1+n2; else if (c==1) s0=n0+n2; else if (c==2) s0=n0+n1+n3; else if (c==3) s0=n2; else s0=0.f;
    float ef = (s0*e0 + ((c==3)? n2*e1 : 0.f) + nc_*e2)*(1.0f/3.0f);
    comb[(size_t)lc*2*EE + e]      = f2bf(nc_);
    comb[(size_t)lc*2*EE + EE + e] = f2bf(ef);
  }
}

__global__ __launch_bounds__(256) void k_sent_init(const float* __restrict__ se, float* __restrict__ sent) {
  const int i = blockIdx.x*256 + threadIdx.x;
  if (i < NB*EE) sent[i] = se[i];
}

// ---------------- graph attention tail (qh precomputed by gemm_skinny) ------
__global__ __launch_bounds__(256) void k_attn2(int l, const float* __restrict__ qhg,
    const float* __restrict__ presence, const float* __restrict__ upd, const float* __restrict__ khg,
    float* __restrict__ sent, float* __restrict__ sc_ws, float* __restrict__ out_scores)
{
  const int b = blockIdx.x, t = threadIdx.x;
  __shared__ float scl[HH][NCC];
  __shared__ float wsc[NCC];
  __shared__ float scr[NCC];
  if (t < HH*NCC) {
    const int hh=t/NCC, cc=t%NCC;
    const float* kr = khg + (size_t)(l*NCC+cc)*EE + hh*DD;
    const float* qr = qhg + (size_t)b*EE + hh*DD;
    float a=0.f;
    #pragma unroll 8
    for (int d=0;d<DD;d++) a += qr[d]*kr[d];
    scl[hh][cc]=a*0.1020620726159658f;
  }
  __syncthreads();
  if (t < HH) {
    float m=scl[t][0];
    #pragma unroll
    for (int c2=1;c2<NCC;c2++) m=fmaxf(m,scl[t][c2]);
    float ex[NCC]; float s=0.f;
    #pragma unroll
    for (int c2=0;c2<NCC;c2++){ ex[c2]=__expf(scl[t][c2]-m); s+=ex[c2]; }
    #pragma unroll
    for (int c2=0;c2<NCC;c2++) scl[t][c2]=ex[c2]/s;
  }
  __syncthreads();
  if (t < NCC) {
    float wv=0.f;
    #pragma unroll
    for (int hh=0;hh<HH;hh++) wv += scl[hh][t];
    wv *= (1.0f/HH);
    wsc[t] = wv*(presence[b*NCC+t]+0.1f);
  }
  __syncthreads();
  if (t==0) {
    float m=wsc[0];
    #pragma unroll
    for (int c2=1;c2<NCC;c2++) m=fmaxf(m,wsc[c2]);
    float ex[NCC]; float s=0.f;
    #pragma unroll
    for (int c2=0;c2<NCC;c2++){ ex[c2]=__expf(wsc[c2]-m); s+=ex[c2]; }
    #pragma unroll
    for (int c2=0;c2<NCC;c2++){
      float v=ex[c2]/s; scr[c2]=v; sc_ws[b*NCC+c2]=v;
      if (out_scores) out_scores[b*NCC+c2]=v;
    }
  }
  __syncthreads();
  #pragma unroll
  for (int i=0;i<3;i++) {
    const int e=t+i*256;
    float a=0.f;
    #pragma unroll
    for (int c2=0;c2<NCC;c2++) a += scr[c2]*upd[(size_t)(l*NCC+c2)*EE+e];
    sent[(size_t)b*EE+e] += a*(1.0f/NCC);
  }
}

// ---------------- act prep: actB[c][b][e] bf16, cat sent half ---------------
__global__ __launch_bounds__(256) void k_actprep(const float* __restrict__ upd, const float* __restrict__ sc_ws,
    const float* __restrict__ sent, u16* __restrict__ actB, u16* __restrict__ cat)
{
  const int bid = blockIdx.x, c = bid/NB, b = bid%NB, t = threadIdx.x;
  const float sc = sc_ws[b*NCC+c];
  #pragma unroll
  for (int i=0;i<3;i++) {
    const int e = t + i*256;
    actB[((size_t)c*NB + b)*EE + e] = f2bf(upd[(size_t)(2*NCC+c)*EE + e]*sc);
    cat[((size_t)(b*NCC+c))*2*EE + EE + e] = f2bf(sent[(size_t)b*EE + e]);
  }
}

// ---------------- fused attention: per (b, h, 64-row q-tile) ----------------
__global__ __launch_bounds__(256) void attn_k(u16* __restrict__ Q, const u16* __restrict__ Kb,
                                              const u16* __restrict__ Vt)
{
  const int qt = blockIdx.x, h = blockIdx.y, b = blockIdx.z;
  const int t = threadIdx.x, l = t&63, w = t>>6, wr = w>>1, wc = w&1, lm = l&15, lg = l>>4;
  __shared__ u16 Ps[64][136];
  __shared__ float redm[2][64];
  __shared__ float reds[2][64];
  u16* qb = Q + ((size_t)(b*PP + qt*64))*EE + h*DD;
  const u16* kb = Kb + ((size_t)b*SEQ)*EE + h*DD;
  const u16* vb = Vt + ((size_t)(b*HH+h))*DD*SEQ;

  f32x4 acc[2][4] = {};
  #pragma unroll
  for (int kc=0;kc<3;kc++) {
    short8 af[2], bv[4];
    #pragma unroll
    for (int mi=0;mi<2;mi++) af[mi] = *(const short8*)(qb + (size_t)(wr*32+mi*16+lm)*EE + kc*32 + lg*8);
    #pragma unroll
    for (int ni=0;ni<4;ni++) bv[ni] = *(const short8*)(kb + (size_t)(wc*64+ni*16+lm)*EE + kc*32 + lg*8);
    #pragma unroll
    for (int mi=0;mi<2;mi++)
      #pragma unroll
      for (int ni=0;ni<4;ni++)
        acc[mi][ni] = __builtin_amdgcn_mfma_f32_16x16x32_bf16(af[mi], bv[ni], acc[mi][ni], 0,0,0);
  }
  const float scale = 0.1020620726159658f; // 1/sqrt(96)
  float gmax[2][4], gsum[2][4];
  #pragma unroll
  for (int mi=0;mi<2;mi++)
    #pragma unroll
    for (int r=0;r<4;r++) {
      float v = fmaxf(fmaxf(acc[mi][0][r],acc[mi][1][r]),fmaxf(acc[mi][2][r],acc[mi][3][r]));
      #pragma unroll
      for (int mk=1;mk<16;mk<<=1) v = fmaxf(v, __shfl_xor(v,mk,64));
      gmax[mi][r]=v;
    }
  if (lm==0) {
    #pragma unroll
    for (int mi=0;mi<2;mi++)
      #pragma unroll
      for (int r=0;r<4;r++) redm[wc][wr*32+mi*16+lg*4+r] = gmax[mi][r];
  }
  __syncthreads();
  #pragma unroll
  for (int mi=0;mi<2;mi++)
    #pragma unroll
    for (int r=0;r<4;r++) {
      const int row = wr*32+mi*16+lg*4+r;
      gmax[mi][r] = fmaxf(redm[0][row], redm[1][row]);
    }
  #pragma unroll
  for (int mi=0;mi<2;mi++)
    #pragma unroll
    for (int r=0;r<4;r++) {
      float s=0.f;
      #pragma unroll
      for (int ni=0;ni<4;ni++) {
        float p = __expf((acc[mi][ni][r]-gmax[mi][r])*scale);
        acc[mi][ni][r]=p; s+=p;
      }
      #pragma unroll
      for (int mk=1;mk<16;mk<<=1) s += __shfl_xor(s,mk,64);
      gsum[mi][r]=s;
    }
  __syncthreads();
  if (lm==0) {
    #pragma unroll
    for (int mi=0;mi<2;mi++)
      #pragma unroll
      for (int r=0;r<4;r++) reds[wc][wr*32+mi*16+lg*4+r] = gsum[mi][r];
  }
  __syncthreads();
  #pragma unroll
  for (int mi=0;mi<2;mi++)
    #pragma unroll
    for (int r=0;r<4;r++) {
      const int row = wr*32+mi*16+lg*4+r;
      const float inv = 1.0f/(reds[0][row]+reds[1][row]);
      #pragma unroll
      for (int ni=0;ni<4;ni++)
        Ps[row][wc*64+ni*16+lm] = f2bf(acc[mi][ni][r]*inv);
    }
  __syncthreads();

  f32x4 oacc[2][3] = {};
  #pragma unroll
  for (int kc=0;kc<4;kc++) {
    short8 pa[2], vv[3];
    #pragma unroll
    for (int mi=0;mi<2;mi++) pa[mi] = *(const short8*)&Ps[wr*32+mi*16+lm][kc*32+lg*8];
    #pragma unroll
    for (int ni=0;ni<3;ni++) vv[ni] = *(const short8*)(vb + (size_t)(wc*48+ni*16+lm)*SEQ + kc*32 + lg*8);
    #pragma unroll
    for (int mi=0;mi<2;mi++)
      #pragma unroll
      for (int ni=0;ni<3;ni++)
        oacc[mi][ni] = __builtin_amdgcn_mfma_f32_16x16x32_bf16(pa[mi], vv[ni], oacc[mi][ni], 0,0,0);
  }
  #pragma unroll
  for (int mi=0;mi<2;mi++)
    #pragma unroll
    for (int ni=0;ni<3;ni++)
      #pragma unroll
      for (int r=0;r<4;r++)
        qb[(size_t)(wr*32+mi*16+lg*4+r)*EE + wc*48+ni*16+lm] = f2bf(oacc[mi][ni][r]);
}

// ---------------- row LayerNorm in-place (bf16 data, f32 params) -------------
__global__ __launch_bounds__(256) void k_ln(u16* __restrict__ G, const float* __restrict__ gw, const float* __restrict__ gb)
{
  const int row = blockIdx.x, t = threadIdx.x;
  u16* p = G + (size_t)row*EE;
  __shared__ float red[8];
  float v[3];
  #pragma unroll
  for (int i=0;i<3;i++) v[i]=bf2f(p[t+i*256]);
  float mean, rstd;
  ln_stats(v[0],v[1],v[2], red, t, mean, rstd);
  #pragma unroll
  for (int i=0;i<3;i++) {
    const int e=t+i*256;
    p[e]=f2bf((v[i]-mean)*rstd*gw[e]+gb[e]);
  }
}

// ---------------- host launch ------------------------------------------------
extern "C" void kernel_launch(void* const* d_in, const int* in_sizes, int n_in,
                              void* d_out, int out_size, void* d_ws, size_t ws_size,
                              hipStream_t stream)
{
  const float* visual   = (const float*)d_in[0];
  const float* text     = (const float*)d_in[1];
  const float* sentemb  = (const float*)d_in[2];
  const float* presence = (const float*)d_in[3];
  const float* gnode = (const float*)d_in[4];
  const float* gedge = (const float*)d_in[5];
  const float* gWqkv = (const float*)d_in[6];
  const float* gbqkv = (const float*)d_in[7];
  const float* gW1 = (const float*)d_in[10];
  const float* gb1 = (const float*)d_in[11];
  const float* glng = (const float*)d_in[12];
  const float* glnb = (const float*)d_in[13];
  const float* gW2 = (const float*)d_in[14];
  const float* gb2 = (const float*)d_in[15];
  const float* vWqkv = (const float*)d_in[16];
  const float* vbqkv = (const float*)d_in[17];
  const float* vWo = (const float*)d_in[18];
  const float* vbo = (const float*)d_in[19];
  const float* cW1 = (const float*)d_in[20];
  const float* cb1 = (const float*)d_in[21];
  const float* clng = (const float*)d_in[22];
  const float* clnb = (const float*)d_in[23];
  const float* cW2 = (const float*)d_in[24];
  const float* cb2 = (const float*)d_in[25];
  const float* gfW1 = (const float*)d_in[26];
  const float* gfb1 = (const float*)d_in[27];
  const float* gflng = (const float*)d_in[28];
  const float* gflnb = (const float*)d_in[29];
  const float* gfW2 = (const float*)d_in[30];
  const float* gfb2 = (const float*)d_in[31];
  const float* outW = (const float*)d_in[32];
  const float* outb = (const float*)d_in[33];
  const float* normg = (const float*)d_in[34];
  const float* normb = (const float*)d_in[35];

  // ---- d_ws layout (<= 113,246,208 B, proven safe) ----
  char* ws = (char*)d_ws;
  u16* wsG   = (u16*)(ws);                    // 32768x768 bf16 (pre-LN / grounded)
  u16* wsK   = (u16*)(ws + 50331648);         // 4096x768 bf16 (attn K); dead after attn
  u16* wsVt  = (u16*)(ws + 56623104);         // V^T bf16
  u16* visB  = (u16*)(ws + 62914560);         // visual bf16 32768x768
  u16* outWB = wsK;                           // outW bf16 overlays dead wsK post-attn

  // ---- d_out scratch (everything < 100.66 MB dead before out-proj writes) ----
  char* dob = (char*)d_out;
  u16* wsQ    = (u16*)(dob);                  // 32768x768 bf16 (Q / attn out)
  u16* textB  = (u16*)(dob + 50331648);       // 4096x768 bf16
  u16* WqkvB  = (u16*)(dob + 56623104);       // 2304x768 bf16
  u16* WoB    = (u16*)(dob + 60162048);       // 768x768 bf16
  char* P = dob + 61341696;                   // graph/class scratch (~2.6 MB)
  float* wsSent   = (float*)(P);
  float* wsUpd    = (float*)(P +   98304);
  float* wsKhg    = (float*)(P +  144384);
  float* wsScores = (float*)(P +  190464);
  u16*   wsComb   = (u16*)  (P +  191104);
  float* wsH      = (float*)(P +  237184);
  u16*   wsHb     = (u16*)  (P +  283264);
  u16*   wsUpdB   = (u16*)  (P +  306304);
  u16*   wsActB   = (u16*)  (P +  329344);
  float* wsH1     = (float*)(P +  575104);
  u16*   wsH1b    = (u16*)  (P + 1066624);
  u16*   wsCat    = (u16*)  (P + 1312384);
  float* wsG1     = (float*)(P + 1803904);
  u16*   wsG1b    = (u16*)  (P + 2295424);
  float* wsQh     = (float*)(P + 2541184);

  float* outGO = (float*)d_out;
  float* outCG = outGO + 25165824;
  float* outSC = outGO + 25288704;

  // ---- conversions ----
  k_cvt<<<dim3(2048), dim3(256), 0, stream>>>(visual, visB, 3145728);
  k_cvt<<<dim3(1024), dim3(256), 0, stream>>>(text, textB, 393216);
  k_cvt<<<dim3(512),  dim3(256), 0, stream>>>(vWqkv, WqkvB, 221184);
  k_cvt<<<dim3(512),  dim3(256), 0, stream>>>(vWo, WoB, 73728);

  // ---- graph node-update chain ----
  k_comb<<<dim3(NLL*NCC), dim3(256), 0, stream>>>(gnode, gedge, wsComb);
  gemm_skinny<16,1,0><<<dim3(6,NLL), dim3(256), 0, stream>>>(wsComb, gW1, gb1, wsH, nullptr,
      NCC, 2*EE, 2*EE, (long)NCC*2*EE, (long)EE*2*EE, (long)EE, EE, (long)NCC*EE, 0, 0);
  k_lnrelu<<<dim3(NLL*NCC), dim3(256), 0, stream>>>(wsH, wsHb, glng, glnb, NCC);
  gemm_skinny<16,3,0><<<dim3(6,NLL), dim3(256), 0, stream>>>(wsHb, gW2, gb2, wsUpd, wsUpdB,
      NCC, EE, EE, (long)NCC*EE, (long)EE*EE, (long)EE, EE, (long)NCC*EE, EE, (long)NCC*EE);
  gemm_skinny<16,1,0><<<dim3(6,NLL), dim3(256), 0, stream>>>(wsUpdB, gWqkv + (size_t)EE*EE, gbqkv + EE, wsKhg, nullptr,
      NCC, EE, EE, (long)NCC*EE, (long)3*EE*EE, (long)3*EE, EE, (long)NCC*EE, 0, 0);

  // ---- sentence loop: qh via skinny GEMM (weights read once), then tail ----
  k_sent_init<<<dim3(96), dim3(256), 0, stream>>>(sentemb, wsSent);
  for (int l=0;l<NLL;l++) {
    gemm_skinny<32,1,1><<<dim3(6,1), dim3(256), 0, stream>>>(wsSent, gWqkv + (size_t)l*3*EE*EE,
        gbqkv + (size_t)l*3*EE, wsQh, nullptr,
        NB, EE, EE, 0, 0, 0, EE, 0, 0, 0);
    k_attn2<<<dim3(NB), dim3(256), 0, stream>>>(l, wsQh, presence, wsUpd, wsKhg,
        wsSent, wsScores, (l==NLL-1)?outSC:(float*)nullptr);
  }

  // ---- class guidance chain ----
  k_actprep<<<dim3(NCC*NB), dim3(256), 0, stream>>>(wsUpd, wsScores, wsSent, wsActB, wsCat);
  gemm_skinny<32,1,0><<<dim3(6,NCC), dim3(256), 0, stream>>>(wsActB, cW1, cb1, wsH1, nullptr,
      NB, EE, EE, (long)NB*EE, (long)EE*EE, (long)EE, EE, (long)NB*EE, 0, 0);
  k_lnrelu<<<dim3(NCC*NB), dim3(256), 0, stream>>>(wsH1, wsH1b, clng, clnb, NB);
  gemm_skinny<32,2,0><<<dim3(6,NCC), dim3(256), 0, stream>>>(wsH1b, cW2, cb2, nullptr, wsCat,
      NB, EE, EE, (long)NB*EE, (long)EE*EE, (long)EE, 0, 0, NCC*2*EE, (long)2*EE);
  gemm_skinny<160,1,0><<<dim3(6,1), dim3(256), 0, stream>>>(wsCat, gfW1, gfb1, wsG1, nullptr,
      NB*NCC, 2*EE, 2*EE, 0, 0, 0, EE, 0, 0, 0);
  k_lnrelu<<<dim3(NB*NCC), dim3(256), 0, stream>>>(wsG1, wsG1b, gflng, gflnb, NB*NCC);
  gemm_skinny<160,1,0><<<dim3(6,1), dim3(256), 0, stream>>>(wsG1b, gfW2, gfb2, outCG, nullptr,
      NB*NCC, EE, EE, 0, 0, 0, EE, 0, 0, 0);

  // ---- visual-text fusion ----
  gemm_bt<0><<<dim3(256,6), dim3(256), 0, stream>>>(visB, WqkvB, vbqkv, nullptr,
                                                    wsQ, nullptr, nullptr, NB*PP, EE, EE);
  gemm_bt<2><<<dim3(32,12), dim3(256), 0, stream>>>(textB, WqkvB + (size_t)EE*EE, vbqkv+EE, nullptr,
                                                    wsK, nullptr, wsVt, NB*SEQ, 2*EE, EE);
  attn_k<<<dim3(PP/64, HH, NB), dim3(256), 0, stream>>>(wsQ, wsK, wsVt);
  k_cvt<<<dim3(512), dim3(256), 0, stream>>>(outW, outWB, 73728);   // into dead wsK
  gemm_bt<1><<<dim3(256,6), dim3(256), 0, stream>>>(wsQ, WoB, vbo, visB,
                                                    wsG, nullptr, nullptr, NB*PP, EE, EE);
  k_ln<<<dim3(NB*PP), dim3(256), 0, stream>>>(wsG, normg, normb);
  gemm_bt<3><<<dim3(256,6), dim3(256), 0, stream>>>(wsG, outWB, outb, nullptr,
                                                    nullptr, outGO, nullptr, NB*PP, EE, EE);
}